// Round 5
// baseline (178.202 us; speedup 1.0000x reference)
//
#include <hip/hip_runtime.h>

// Smoother: out = max(pred, (reflect-pad moving-sum(K=501) + bias)/K)
// pred: [B=8, T=16384, C=128] fp32.
// Round 5: force memory-level parallelism with explicit double-buffered
// register banks (compiler was collapsing unrolls to ~2 loads in flight:
// VGPR=32 in r4). f2 lanes = full 128-ch row per wave; 1024 waves;
// batch-per-XCD swizzle; nontemporal stores.

typedef float f2 __attribute__((ext_vector_type(2)));

constexpr int B  = 8;
constexpr int T  = 16384;
constexpr int C  = 128;
constexpr int K  = 501;
constexpr int Pp = 250;
constexpr int TT = 128;    // outputs per wave (one tile per wave)
constexpr int PF = 8;      // software-pipeline group size (iterations)
constexpr int BLOCK = 128; // 2 waves -> 2 adjacent tiles per block
constexpr int RS = C / 2;  // row stride in f2 units (64)

__device__ __forceinline__ int ridx(int j) {
    j = (j < 0) ? -j : j;
    return (j >= T) ? (2 * T - 2 - j) : j;
}

__global__ __launch_bounds__(BLOCK) void smoother_kernel(
    const float* __restrict__ pred, const float* __restrict__ bias,
    float* __restrict__ out) {
    // 512 blocks. XCD swizzle: batch b = blockIdx&7 -> one batch per XCD.
    const int b    = blockIdx.x & 7;
    const int pair = blockIdx.x >> 3;          // 0..63
    const int wave = threadIdx.x >> 6;         // 0..1
    const int lane = threadIdx.x & 63;
    const int t0   = (pair * 2 + wave) * TT;

    const f2* base  = (const f2*)(pred + (size_t)b * T * C) + lane;
    f2*       obase = (f2*)(out + (size_t)b * T * C) + lane;

    const float rk  = 1.0f / (float)K;
    const float brk = bias[0] * rk;

    const bool interior = (t0 - Pp >= 0) && (t0 + TT + Pp < T);

    if (interior) {
        // ================= init: rows [t0-250, t0+250] =================
        // Double-buffered banks LA/LB (8 each) against acc[8]: keeps ~16
        // f2 loads (8 KB) outstanding at all times.
        const f2* p = base + (t0 - Pp) * RS;
        f2 acc[8], LA[8], LB[8];
        #pragma unroll
        for (int u = 0; u < 8; ++u) { acc[u] = (f2){0.f, 0.f}; }
        #pragma unroll
        for (int u = 0; u < 8; ++u) LA[u] = p[u * RS];
        int j = 0;
        for (; j + 24 <= K; j += 16) {          // j = 0..464, 30 iters
            #pragma unroll
            for (int u = 0; u < 8; ++u) LB[u] = p[(j + 8 + u) * RS];
            #pragma unroll
            for (int u = 0; u < 8; ++u) acc[u] += LA[u];
            #pragma unroll
            for (int u = 0; u < 8; ++u) LA[u] = p[(j + 16 + u) * RS];
            #pragma unroll
            for (int u = 0; u < 8; ++u) acc[u] += LB[u];
        }
        #pragma unroll
        for (int u = 0; u < 8; ++u) acc[u] += LA[u];   // rows 480..487
        for (int r = j + 8; r < K; ++r)                // rows 488..500
            acc[r & 7] += p[r * RS];
        f2 s = ((acc[0] + acc[1]) + (acc[2] + acc[3]))
             + ((acc[4] + acc[5]) + (acc[6] + acc[7]));

        // ================= slide: software-pipelined ===================
        // Banks A/B: each holds PF iterations x 3 streams = 24 f2 loads
        // (12 KB) in flight while the other bank computes.
        f2 Anw[PF], Aod[PF], Acen[PF];
        f2 Bnw[PF], Bod[PF], Bcen[PF];

        auto loadg = [&](f2* NW, f2* OD, f2* CEN, int t) {
            #pragma unroll
            for (int u = 0; u < PF; ++u) {
                CEN[u] = base[(t + u) * RS];
                NW[u]  = base[(t + u + Pp + 1) * RS];
                OD[u]  = base[(t + u - Pp) * RS];
            }
        };
        auto computeg = [&](const f2* NW, const f2* OD, const f2* CEN, int t) {
            #pragma unroll
            for (int u = 0; u < PF; ++u) {
                f2 o;
                o.x = fmaxf(CEN[u].x, fmaf(s.x, rk, brk));
                o.y = fmaxf(CEN[u].y, fmaf(s.y, rk, brk));
                __builtin_nontemporal_store(o, &obase[(t + u) * RS]);
                s += NW[u] - OD[u];
            }
        };

        int t = t0;
        loadg(Anw, Aod, Acen, t);
        #pragma unroll
        for (int g = 0; g < TT / (2 * PF); ++g) {      // 8 iterations
            loadg(Bnw, Bod, Bcen, t + PF);
            computeg(Anw, Aod, Acen, t);
            if (g + 1 < TT / (2 * PF))
                loadg(Anw, Aod, Acen, t + 2 * PF);
            computeg(Bnw, Bod, Bcen, t + PF);
            t += 2 * PF;
        }
    } else {
        // ================= boundary path (4 tiles per batch) ===========
        f2 s = {0.f, 0.f};
        #pragma unroll 4
        for (int j = t0 - Pp; j <= t0 + Pp; ++j)
            s += base[ridx(j) * RS];
        #pragma unroll 2
        for (int t = t0; t < t0 + TT; ++t) {
            f2 cen = base[t * RS];
            f2 nw  = base[ridx(t + Pp + 1) * RS];
            f2 od  = base[ridx(t - Pp) * RS];
            f2 o;
            o.x = fmaxf(cen.x, fmaf(s.x, rk, brk));
            o.y = fmaxf(cen.y, fmaf(s.y, rk, brk));
            __builtin_nontemporal_store(o, &obase[t * RS]);
            s += nw - od;
        }
    }
}

extern "C" void kernel_launch(void* const* d_in, const int* in_sizes, int n_in,
                              void* d_out, int out_size, void* d_ws, size_t ws_size,
                              hipStream_t stream) {
    const float* pred = (const float*)d_in[0];
    const float* bias = (const float*)d_in[1];
    float*       out  = (float*)d_out;

    const int blocks = B * (T / TT) / 2;   // 512
    smoother_kernel<<<blocks, BLOCK, 0, stream>>>(pred, bias, out);
}

// Round 6
// 178.181 us; speedup vs baseline: 1.0001x; 1.0001x over previous
//
#include <hip/hip_runtime.h>

// Smoother: out = max(pred, (reflect-pad moving-sum(K=501) + bias)/K)
// pred: [B=8, T=16384, C=128] fp32.
// Round 6 = round 5 + __launch_bounds__(BLOCK, 1).
// r3/r4/r5 all plateaued at ~95us = 885 loads x ~258cy serial chain per wave:
// the compiler's max-occupancy pressure target sank every load to its use
// (VGPR=36 despite 96+ worth of explicit banks). waves_per_eu=1 relaxes the
// register budget to ~512 so the double-buffered banks can stay live and
// 16-24 loads stay in flight per wave. We only run 4 waves/CU anyway, so
// the occupancy "cost" is zero.

typedef float f2 __attribute__((ext_vector_type(2)));

constexpr int B  = 8;
constexpr int T  = 16384;
constexpr int C  = 128;
constexpr int K  = 501;
constexpr int Pp = 250;
constexpr int TT = 128;    // outputs per wave (one tile per wave)
constexpr int PF = 8;      // software-pipeline group size (iterations)
constexpr int BLOCK = 128; // 2 waves -> 2 adjacent tiles per block
constexpr int RS = C / 2;  // row stride in f2 units (64)

__device__ __forceinline__ int ridx(int j) {
    j = (j < 0) ? -j : j;
    return (j >= T) ? (2 * T - 2 - j) : j;
}

__global__ __launch_bounds__(BLOCK, 1) void smoother_kernel(
    const float* __restrict__ pred, const float* __restrict__ bias,
    float* __restrict__ out) {
    // 512 blocks. XCD swizzle: batch b = blockIdx&7 -> one batch per XCD.
    const int b    = blockIdx.x & 7;
    const int pair = blockIdx.x >> 3;          // 0..63
    const int wave = threadIdx.x >> 6;         // 0..1
    const int lane = threadIdx.x & 63;
    const int t0   = (pair * 2 + wave) * TT;

    const f2* base  = (const f2*)(pred + (size_t)b * T * C) + lane;
    f2*       obase = (f2*)(out + (size_t)b * T * C) + lane;

    const float rk  = 1.0f / (float)K;
    const float brk = bias[0] * rk;

    const bool interior = (t0 - Pp >= 0) && (t0 + TT + Pp < T);

    if (interior) {
        // ================= init: rows [t0-250, t0+250] =================
        // Double-buffered banks LA/LB (8 each) against acc[8]: ~16 f2
        // loads (8 KB) outstanding at all times.
        const f2* p = base + (t0 - Pp) * RS;
        f2 acc[8], LA[8], LB[8];
        #pragma unroll
        for (int u = 0; u < 8; ++u) { acc[u] = (f2){0.f, 0.f}; }
        #pragma unroll
        for (int u = 0; u < 8; ++u) LA[u] = p[u * RS];
        int j = 0;
        for (; j + 24 <= K; j += 16) {          // j = 0..480, 31 iters
            #pragma unroll
            for (int u = 0; u < 8; ++u) LB[u] = p[(j + 8 + u) * RS];
            #pragma unroll
            for (int u = 0; u < 8; ++u) acc[u] += LA[u];
            #pragma unroll
            for (int u = 0; u < 8; ++u) LA[u] = p[(j + 16 + u) * RS];
            #pragma unroll
            for (int u = 0; u < 8; ++u) acc[u] += LB[u];
        }
        #pragma unroll
        for (int u = 0; u < 8; ++u) acc[u] += LA[u];   // rows 480..487
        for (int r = j + 8; r < K; ++r)                // rows 488..500
            acc[r & 7] += p[r * RS];
        f2 s = ((acc[0] + acc[1]) + (acc[2] + acc[3]))
             + ((acc[4] + acc[5]) + (acc[6] + acc[7]));

        // ================= slide: software-pipelined ===================
        // Banks A/B: each holds PF iterations x 3 streams = 24 f2 loads
        // (12 KB) in flight while the other bank computes.
        f2 Anw[PF], Aod[PF], Acen[PF];
        f2 Bnw[PF], Bod[PF], Bcen[PF];

        auto loadg = [&](f2* NW, f2* OD, f2* CEN, int t) {
            #pragma unroll
            for (int u = 0; u < PF; ++u) {
                CEN[u] = base[(t + u) * RS];
                NW[u]  = base[(t + u + Pp + 1) * RS];
                OD[u]  = base[(t + u - Pp) * RS];
            }
        };
        auto computeg = [&](const f2* NW, const f2* OD, const f2* CEN, int t) {
            #pragma unroll
            for (int u = 0; u < PF; ++u) {
                f2 o;
                o.x = fmaxf(CEN[u].x, fmaf(s.x, rk, brk));
                o.y = fmaxf(CEN[u].y, fmaf(s.y, rk, brk));
                __builtin_nontemporal_store(o, &obase[(t + u) * RS]);
                s += NW[u] - OD[u];
            }
        };

        int t = t0;
        loadg(Anw, Aod, Acen, t);
        #pragma unroll
        for (int g = 0; g < TT / (2 * PF); ++g) {      // 8 iterations
            loadg(Bnw, Bod, Bcen, t + PF);
            computeg(Anw, Aod, Acen, t);
            if (g + 1 < TT / (2 * PF))
                loadg(Anw, Aod, Acen, t + 2 * PF);
            computeg(Bnw, Bod, Bcen, t + PF);
            t += 2 * PF;
        }
    } else {
        // ================= boundary path (4 tiles per batch) ===========
        f2 s = {0.f, 0.f};
        #pragma unroll 4
        for (int j = t0 - Pp; j <= t0 + Pp; ++j)
            s += base[ridx(j) * RS];
        #pragma unroll 2
        for (int t = t0; t < t0 + TT; ++t) {
            f2 cen = base[t * RS];
            f2 nw  = base[ridx(t + Pp + 1) * RS];
            f2 od  = base[ridx(t - Pp) * RS];
            f2 o;
            o.x = fmaxf(cen.x, fmaf(s.x, rk, brk));
            o.y = fmaxf(cen.y, fmaf(s.y, rk, brk));
            __builtin_nontemporal_store(o, &obase[t * RS]);
            s += nw - od;
        }
    }
}

extern "C" void kernel_launch(void* const* d_in, const int* in_sizes, int n_in,
                              void* d_out, int out_size, void* d_ws, size_t ws_size,
                              hipStream_t stream) {
    const float* pred = (const float*)d_in[0];
    const float* bias = (const float*)d_in[1];
    float*       out  = (float*)d_out;

    const int blocks = B * (T / TT) / 2;   // 512
    smoother_kernel<<<blocks, BLOCK, 0, stream>>>(pred, bias, out);
}

// Round 7
// 174.570 us; speedup vs baseline: 1.0208x; 1.0207x over previous
//
#include <hip/hip_runtime.h>

// Smoother: out = max(pred, (reflect-pad moving-sum(K=501) + bias)/K)
// pred: [B=8, T=16384, C=128] fp32.
// Round 7 = round 6 + __builtin_amdgcn_sched_barrier(0) fences pinning
// load-group / compute-group order. r4-r6: scheduler sank every load to its
// use (VGPR stuck at 36) -> 1 load in flight -> 885 x 260cy = 95us plateau.
// sched_barrier(0) is un-undoable: banks must stay live, waitcnts become
// vmcnt(N) group waits, ~16-24 loads in flight per wave.

typedef float f2 __attribute__((ext_vector_type(2)));

#define SBAR() __builtin_amdgcn_sched_barrier(0)

constexpr int B  = 8;
constexpr int T  = 16384;
constexpr int C  = 128;
constexpr int K  = 501;
constexpr int Pp = 250;
constexpr int TT = 128;    // outputs per wave (one tile per wave)
constexpr int PF = 8;      // slide pipeline group (iterations per bank)
constexpr int BLOCK = 128; // 2 waves -> 2 adjacent tiles per block
constexpr int RS = C / 2;  // row stride in f2 units (64)

__device__ __forceinline__ int ridx(int j) {
    j = (j < 0) ? -j : j;
    return (j >= T) ? (2 * T - 2 - j) : j;
}

__global__ __launch_bounds__(BLOCK, 1) void smoother_kernel(
    const float* __restrict__ pred, const float* __restrict__ bias,
    float* __restrict__ out) {
    // 512 blocks. XCD swizzle: batch b = blockIdx&7 -> one batch per XCD.
    const int b    = blockIdx.x & 7;
    const int pair = blockIdx.x >> 3;          // 0..63
    const int wave = threadIdx.x >> 6;         // 0..1
    const int lane = threadIdx.x & 63;
    const int t0   = (pair * 2 + wave) * TT;

    const f2* base  = (const f2*)(pred + (size_t)b * T * C) + lane;
    f2*       obase = (f2*)(out + (size_t)b * T * C) + lane;

    const float rk  = 1.0f / (float)K;
    const float brk = bias[0] * rk;

    const bool interior = (t0 - Pp >= 0) && (t0 + TT + Pp < T);

    if (interior) {
        // ================= init: rows [t0-250, t0+250] =================
        // 16-row groups, double-buffered LA/LB, sched_barrier-pinned.
        const f2* p = base + (t0 - Pp) * RS;
        f2 acc[16], LA[16], LB[16];
        #pragma unroll
        for (int u = 0; u < 16; ++u) acc[u] = (f2){0.f, 0.f};
        #pragma unroll
        for (int u = 0; u < 16; ++u) LA[u] = p[u * RS];   // group 0: rows 0..15
        SBAR();
        // groups 1..30 (rows 16..495), pairs per iteration
        for (int g = 1; g + 1 < 31; g += 2) {             // 15 iterations
            const f2* pb = p + g * 16 * RS;
            #pragma unroll
            for (int u = 0; u < 16; ++u) LB[u] = pb[u * RS];
            SBAR();
            #pragma unroll
            for (int u = 0; u < 16; ++u) acc[u] += LA[u];
            SBAR();
            const f2* pa = p + (g + 1) * 16 * RS;
            #pragma unroll
            for (int u = 0; u < 16; ++u) LA[u] = pa[u * RS];
            SBAR();
            #pragma unroll
            for (int u = 0; u < 16; ++u) acc[u] += LB[u];
            SBAR();
        }
        #pragma unroll
        for (int u = 0; u < 16; ++u) acc[u] += LA[u];     // rows 480..495
        #pragma unroll
        for (int u = 0; u < 5; ++u)                       // rows 496..500
            acc[u] += p[(496 + u) * RS];
        #pragma unroll
        for (int w = 8; w >= 1; w >>= 1)
            #pragma unroll
            for (int u = 0; u < w; ++u) acc[u] += acc[u + w];
        f2 s = acc[0];

        // ================= slide: software-pipelined ===================
        // Banks A/B: PF iters x 3 streams = 24 f2 loads in flight each.
        f2 Anw[PF], Aod[PF], Acen[PF];
        f2 Bnw[PF], Bod[PF], Bcen[PF];

        auto loadg = [&](f2* NW, f2* OD, f2* CEN, int t) {
            #pragma unroll
            for (int u = 0; u < PF; ++u) {
                CEN[u] = base[(t + u) * RS];
                NW[u]  = base[(t + u + Pp + 1) * RS];
                OD[u]  = base[(t + u - Pp) * RS];
            }
        };
        auto computeg = [&](const f2* NW, const f2* OD, const f2* CEN, int t) {
            #pragma unroll
            for (int u = 0; u < PF; ++u) {
                f2 o;
                o.x = fmaxf(CEN[u].x, fmaf(s.x, rk, brk));
                o.y = fmaxf(CEN[u].y, fmaf(s.y, rk, brk));
                __builtin_nontemporal_store(o, &obase[(t + u) * RS]);
                s += NW[u] - OD[u];
            }
        };

        int t = t0;
        loadg(Anw, Aod, Acen, t);
        SBAR();
        #pragma unroll
        for (int g = 0; g < TT / (2 * PF); ++g) {      // 8 iterations
            loadg(Bnw, Bod, Bcen, t + PF);
            SBAR();
            computeg(Anw, Aod, Acen, t);
            SBAR();
            if (g + 1 < TT / (2 * PF)) {
                loadg(Anw, Aod, Acen, t + 2 * PF);
                SBAR();
            }
            computeg(Bnw, Bod, Bcen, t + PF);
            SBAR();
            t += 2 * PF;
        }
    } else {
        // ================= boundary path (4 tiles per batch) ===========
        f2 s = {0.f, 0.f};
        #pragma unroll 4
        for (int j = t0 - Pp; j <= t0 + Pp; ++j)
            s += base[ridx(j) * RS];
        #pragma unroll 2
        for (int t = t0; t < t0 + TT; ++t) {
            f2 cen = base[t * RS];
            f2 nw  = base[ridx(t + Pp + 1) * RS];
            f2 od  = base[ridx(t - Pp) * RS];
            f2 o;
            o.x = fmaxf(cen.x, fmaf(s.x, rk, brk));
            o.y = fmaxf(cen.y, fmaf(s.y, rk, brk));
            __builtin_nontemporal_store(o, &obase[t * RS]);
            s += nw - od;
        }
    }
}

extern "C" void kernel_launch(void* const* d_in, const int* in_sizes, int n_in,
                              void* d_out, int out_size, void* d_ws, size_t ws_size,
                              hipStream_t stream) {
    const float* pred = (const float*)d_in[0];
    const float* bias = (const float*)d_in[1];
    float*       out  = (float*)d_out;

    const int blocks = B * (T / TT) / 2;   // 512
    smoother_kernel<<<blocks, BLOCK, 0, stream>>>(pred, bias, out);
}

// Round 8
// 149.117 us; speedup vs baseline: 1.1950x; 1.1707x over previous
//
#include <hip/hip_runtime.h>

// Smoother: out = max(pred, (reflect-pad moving-sum(K=501) + bias)/K)
// pred: [B=8, T=16384, C=128] fp32.
// Round 8: LDS ring buffer fed by global_load_lds DMA. r3-r7 analysis:
// issued-bytes pinned at ~6.1 TB/s (per-CU load-return ~10 B/cy) -> with
// 6.9x read amplification we've been AT that roofline since r3. Fix: read
// each row from global ONCE (DMA to LDS ring), serve init/old/cen/new
// streams from LDS. 512 blocks x 1 wave, 16-ch column slices, 8 segments,
// 64 KB ring (1024 rows x 64 B, pow2 mod), quad-row steps with 2-shuffle
// prefix for the serial window recurrence. No barriers anywhere.

constexpr int B    = 8;
constexpr int T    = 16384;
constexpr int C    = 128;
constexpr int K    = 501;
constexpr int Pp   = 250;
constexpr int CHN  = 16;              // channels per block
constexpr int NCG  = C / CHN;         // 8 channel groups
constexpr int NSEG = 8;               // segments per column
constexpr int SEGR = T / NSEG;        // 2048 output rows per block
constexpr int RING = 1024;            // ring rows (pow2 for cheap mod)
constexpr int CHK  = 64;              // staging chunk rows
constexpr int NC   = (SEGR + 512) / CHK;   // 40 chunks: [g0-256, g0+2304)
constexpr int PRO  = 12;              // prologue chunks

__device__ __forceinline__ int ridx(int j) {
    j = (j < 0) ? -j : j;
    return (j >= T) ? (2 * T - 2 - j) : j;
}

__device__ __forceinline__ void dma16(const float* g, float* l) {
    __builtin_amdgcn_global_load_lds(
        (const __attribute__((address_space(1))) void*)g,
        (__attribute__((address_space(3))) void*)l, 16, 0, 0);
}
__device__ __forceinline__ void dma4(const float* g, float* l) {
    __builtin_amdgcn_global_load_lds(
        (const __attribute__((address_space(1))) void*)g,
        (__attribute__((address_space(3))) void*)l, 4, 0, 0);
}

__global__ __launch_bounds__(64) void smoother_kernel(
    const float* __restrict__ pred, const float* __restrict__ bias,
    float* __restrict__ out) {
    __shared__ float ring[RING * CHN];   // 65536 B

    // 512 blocks: b = blockIdx&7 (one batch per XCD), cg, seg.
    const int b   = blockIdx.x & 7;
    const int cg  = (blockIdx.x >> 3) & 7;
    const int seg = blockIdx.x >> 6;
    const int g0  = seg * SEGR;
    const int jstart = g0 - 256;         // ring phase 0 = row jstart

    const int lane = threadIdx.x & 63;
    const int q    = lane >> 4;          // row-in-quad 0..3
    const int ch   = lane & 15;          // channel within group

    const float* pb = pred + (size_t)b * T * C;
    float*       ob = out  + (size_t)b * T * C + cg * CHN + ch;

    const float rk  = 1.0f / (float)K;
    const float brk = bias[0] * rk;

    // ---- chunk stager: DMA 64 rows (chunk m) into the ring ----
    auto stage = [&](int m) {
        const int j0  = jstart + m * CHK;
        const int ph0 = (m * CHK) & (RING - 1);
        if (j0 >= 0 && j0 + CHK - 1 < T) {
            // interior: 4 instrs x (16 rows x 64 B = 1 KB)
            #pragma unroll
            for (int i = 0; i < 4; ++i) {
                const float* g = pb + (size_t)(j0 + 16 * i + (lane >> 2)) * C
                               + cg * CHN + (lane & 3) * 4;
                dma16(g, &ring[(size_t)(ph0 + 16 * i) * CHN]);
            }
        } else {
            // boundary (reflect): 16 instrs x (4 rows x 64 B)
            #pragma unroll
            for (int i = 0; i < 16; ++i) {
                const int jr = ridx(j0 + 4 * i + (lane >> 4));
                const float* g = pb + (size_t)jr * C + cg * CHN + (lane & 15);
                dma4(g, &ring[(size_t)(ph0 + 4 * i) * CHN]);
            }
        }
    };

    // ---- prologue: stage chunks 0..PRO-1 (covers seed window + margin) ----
    for (int m = 0; m < PRO; ++m) stage(m);

    // ---- seed: S = sum rows [g0-250, g0+250]  (phases 6..506) ----
    float acc = 0.0f;
    #pragma unroll 5
    for (int i = 0; i < 125; ++i)
        acc += ring[(size_t)(6 + 4 * i + q) * CHN + ch];
    float a2 = acc + __shfl_xor(acc, 16);
    float S  = a2 + __shfl_xor(a2, 32);
    S += ring[(size_t)506 * CHN + ch];

    // ---- slide: 32 process-chunks x 16 quad-steps (4 outputs each) ----
    int rn = 507 + q;   // phase of row my_t+251
    int ro = 6   + q;   // phase of row my_t-250
    int rc = 256 + q;   // phase of row my_t
    int my_t = g0 + q;

    for (int k = 0; k < SEGR / CHK; ++k) {
        #pragma unroll 4
        for (int i = 0; i < CHK / 4; ++i) {
            const float vn = ring[(size_t)rn * CHN + ch];
            const float vo = ring[(size_t)ro * CHN + ch];
            const float vc = ring[(size_t)rc * CHN + ch];
            const float d  = vn - vo;
            // inclusive prefix of d over the quad (Hillis-Steele, 2 shfl)
            float x = d;
            const float u1 = __shfl_up(x, 16); if (lane >= 16) x += u1;
            const float u2 = __shfl_up(x, 32); if (lane >= 32) x += u2;
            const float tot = __shfl(x, 48 + ch);   // quad total, per channel
            const float sm  = S + (x - d);          // exclusive prefix
            const float o   = fmaxf(vc, fmaf(sm, rk, brk));
            __builtin_nontemporal_store(o, &ob[(size_t)my_t * C]);
            S += tot;
            rn = (rn + 4) & (RING - 1);
            ro = (ro + 4) & (RING - 1);
            rc = (rc + 4) & (RING - 1);
            my_t += 4;
        }
        if (PRO + k < NC) stage(PRO + k);
    }
}

extern "C" void kernel_launch(void* const* d_in, const int* in_sizes, int n_in,
                              void* d_out, int out_size, void* d_ws, size_t ws_size,
                              hipStream_t stream) {
    const float* pred = (const float*)d_in[0];
    const float* bias = (const float*)d_in[1];
    float*       out  = (float*)d_out;

    const int blocks = B * NCG * NSEG;   // 512
    smoother_kernel<<<blocks, 64, 0, stream>>>(pred, bias, out);
}